// Round 8
// baseline (66903.394 us; speedup 1.0000x reference)
//
#include <hip/hip_runtime.h>
#include <math.h>

// Problem constants
#define NB     16
#define NW     64
#define NK     1024
#define NPX    1024
#define NVIS_  65536
#define NMEM   15        // member WGs per batch
#define TPB    256
#define NWG    256       // 240 members + 16 sequencers
#define WWIN   5         // Gram window: member posts s_{j+5} at step j
#define NDC    4         // corrections d=1..4

// ws word offsets
#define WS_ROOTA   0
#define WS_ROOTB   16
#define WS_GMAX    288        // 64 slots
#define WS_LEAFB   512
#define WS_SRING_W 2048       // [16 b][8 slot][15 m][64 w] x 16B  (491,520 w)
#define WS_RRING_W 493568     // [16 b][8 slot][64 w] x 16B        (32,768 w)
#define WS_X0P_W   526336     // [32 kwc][16 b][1024 px][2] f32    (1,048,576 w)
#define WS_TAU_W   1574912    // [16 b][1024 k][64 w] f32          (1,048,576 w)
#define WS_G_W     2623488    // [1024 j][4 d][64 c][64 w] u32 bf16pair (16,777,216 w -> 77.6MB total)
#define INIT_W     526336

#define AG_LDF(p)    __hip_atomic_load((p), __ATOMIC_RELAXED, __HIP_MEMORY_SCOPE_AGENT)
#define AG_STF(p,v)  __hip_atomic_store((p), (v), __ATOMIC_RELAXED, __HIP_MEMORY_SCOPE_AGENT)
#define AG_STU(p,v)  __hip_atomic_store((p), (v), __ATOMIC_RELAXED, __HIP_MEMORY_SCOPE_AGENT)
#define AG_ST64(p,v) __hip_atomic_store((p), (v), __ATOMIC_RELAXED, __HIP_MEMORY_SCOPE_AGENT)

// raw barrier: drains LDS only; global loads stay in flight (compiler-counted vmcnt)
#define BARL() do { asm volatile("s_waitcnt lgkmcnt(0)" ::: "memory"); \
                    __builtin_amdgcn_s_barrier(); } while (0)

#define ESTR 164   // redc e-stride: 164 % 32 == 4 -> <=2-way on reduction reads

typedef struct {
  float xs[160];            // x slice (<=72 px * 2)
  float rsbuf[2][128];      // r ring (double buffer)
  float partl[128];         // A-phase partials handoff to wave0
  float redc[8 * ESTR];     // C-phase cross-wave reduction [e][wsub*20+g5]
  float axs[128];
} MemSM;
typedef struct {
  float wE[NW * 65], wU[NW * 65], wM[NW * 65];
  float bE[NW], bU[NW], bM[NW];
  float ztA[128], ztB[128];
  float rloc[4][128];       // r ring for Gram corrections (d<=4)
  float rpost[128];
  float r2s[NW], tpl[NW], hts[NW];
} SeqSM;
typedef struct { float ysr[2048], ysi[2048]; } X0SM;
typedef union { MemSM m; SeqSM q; X0SM x; } SMem;

__global__ void robbi_init(unsigned* ws) {
  for (int i = blockIdx.x * blockDim.x + threadIdx.x; i < INIT_W; i += gridDim.x * blockDim.x)
    __hip_atomic_store(ws + i, 0u, __ATOMIC_RELAXED, __HIP_MEMORY_SCOPE_AGENT);
}

__device__ __forceinline__ void gbar(unsigned* root, unsigned* leaf, int leafmod, unsigned ntarget) {
  __syncthreads();
  if (threadIdx.x == 0) {
    unsigned old = __hip_atomic_fetch_add(leaf, 1u, __ATOMIC_ACQ_REL, __HIP_MEMORY_SCOPE_AGENT);
    if ((old % (unsigned)leafmod) == (unsigned)(leafmod - 1))
      __hip_atomic_fetch_add(root, 1u, __ATOMIC_ACQ_REL, __HIP_MEMORY_SCOPE_AGENT);
    while (__hip_atomic_load(root, __ATOMIC_ACQUIRE, __HIP_MEMORY_SCOPE_AGENT) < ntarget)
      __builtin_amdgcn_s_sleep(4);
  }
  __syncthreads();
}

// ---- Gram: G[j][d-1][c][w] = Re/Im(H_j[w] . conj(H_{j+d})[c]) packed bf16 ----
// block = (j, d-pair): d0 = 1 or 3; computes d0, d0+1 with hj staged once.
__global__ __launch_bounds__(256) void robbi_gram(const float* __restrict__ H_re,
                                                  const float* __restrict__ H_im,
                                                  float* ws) {
  const int j = blockIdx.x >> 1;
  const int d0 = 1 + 2 * (blockIdx.x & 1);
  unsigned* Gu = (unsigned*)ws + WS_G_W;
  const int t = threadIdx.x;
  __shared__ float hj[64 * 130];
  __shared__ float hk[64 * 130];
  const int c = t & 63, wg = t >> 6;
  float accr[2][16], acci[2][16];
#pragma unroll
  for (int dd = 0; dd < 2; ++dd)
#pragma unroll
    for (int ii = 0; ii < 16; ++ii) { accr[dd][ii] = 0.f; acci[dd][ii] = 0.f; }

  for (int pc = 0; pc < 16; ++pc) {
    for (int q = t; q < 1024; q += 256) {       // stage hj chunk (once per pc)
      int row = q >> 4, px4 = (q & 15) * 4;
      size_t offj = (size_t)(j * NW + row) * NPX + pc * 64 + px4;
      float4 r4 = *(const float4*)(H_re + offj);
      float4 i4 = *(const float4*)(H_im + offj);
      int b0 = row * 130 + px4 * 2;
      hj[b0+0]=r4.x; hj[b0+1]=i4.x; hj[b0+2]=r4.y; hj[b0+3]=i4.y;
      hj[b0+4]=r4.z; hj[b0+5]=i4.z; hj[b0+6]=r4.w; hj[b0+7]=i4.w;
    }
#pragma unroll
    for (int dd = 0; dd < 2; ++dd) {
      const int k = j + d0 + dd;
      if (k < NK) {
        for (int q = t; q < 1024; q += 256) {
          int row = q >> 4, px4 = (q & 15) * 4;
          size_t offk = (size_t)(k * NW + row) * NPX + pc * 64 + px4;
          float4 r4 = *(const float4*)(H_re + offk);
          float4 i4 = *(const float4*)(H_im + offk);
          int b0 = row * 130 + px4 * 2;
          hk[b0+0]=r4.x; hk[b0+1]=i4.x; hk[b0+2]=r4.y; hk[b0+3]=i4.y;
          hk[b0+4]=r4.z; hk[b0+5]=i4.z; hk[b0+6]=r4.w; hk[b0+7]=i4.w;
        }
      }
      __syncthreads();
      if (k < NK) {
#pragma unroll
        for (int ii = 0; ii < 16; ++ii) {
          const int w = wg * 16 + ii;
          float ar_ = 0.f, ai_ = 0.f;
#pragma unroll 8
          for (int px = 0; px < 64; ++px) {
            float jr = hj[w*130 + px*2], ji = hj[w*130 + px*2 + 1];
            float kr = hk[c*130 + px*2], ki = hk[c*130 + px*2 + 1];
            ar_ += jr*kr + ji*ki;       // Hj . conj(Hk)
            ai_ += ji*kr - jr*ki;
          }
          accr[dd][ii] += ar_; acci[dd][ii] += ai_;
        }
      }
      __syncthreads();
    }
  }
#pragma unroll
  for (int dd = 0; dd < 2; ++dd) {
    const int k = j + d0 + dd;
    if (k < NK) {
#pragma unroll
      for (int ii = 0; ii < 16; ++ii) {
        unsigned br = __float_as_uint(accr[dd][ii]);
        br = (br + 0x7FFFu + ((br >> 16) & 1u)) & 0xFFFF0000u;
        unsigned bi = __float_as_uint(acci[dd][ii]);
        bi = ((bi + 0x7FFFu + ((bi >> 16) & 1u)) >> 16) & 0xFFFFu;
        Gu[((size_t)(j * NDC + (d0 + dd - 1)) * 64 + c) * 64 + wg * 16 + ii] = br | bi;
      }
    }
  }
}

#define GMAC(UU, IDX, RL)                                                       \
  { unsigned uu_ = (UU);                                                        \
    float gr_ = __uint_as_float(uu_ & 0xffff0000u);                             \
    float gi_ = __uint_as_float(uu_ << 16);                                     \
    float rr_ = (RL)[2*(IDX)], ri_ = (RL)[2*(IDX)+1];                           \
    ar += rr_*gr_ - ri_*gi_; ai += rr_*gi_ + ri_*gr_; }

__global__ __launch_bounds__(TPB, 1) void robbi_pipe(
    const float* __restrict__ y_re, const float* __restrict__ y_im,
    const float* __restrict__ H_re, const float* __restrict__ H_im,
    const float* __restrict__ Ew, const float* __restrict__ Eb,
    const float* __restrict__ Uw, const float* __restrict__ Ub,
    const float* __restrict__ Mw, const float* __restrict__ Mb,
    const float* __restrict__ thr_p, const int* __restrict__ niter_p,
    float* __restrict__ out, float* ws) {
  const int bid = blockIdx.x;
  const int t = threadIdx.x;
  unsigned* wsu = (unsigned*)ws;
  const unsigned* Gu = wsu + WS_G_W;
  float* tau = ws + WS_TAU_W;
  __shared__ SMem sm;

  const float thr = *thr_p;
  const int niter = *niter_p;
  const int wsub = t >> 5;
  const int g5 = t & 31;
  const int p4 = 4 * g5;

  // ================= x0 stage 1: all 256 WGs =================
  {
    const int kwc = bid >> 3, ps = bid & 7;
    float ar[2][4], ai[2][4];
#pragma unroll
    for (int h = 0; h < 2; ++h)
#pragma unroll
      for (int j = 0; j < 4; ++j) { ar[h][j] = 0.f; ai[h][j] = 0.f; }
    for (int slab = 0; slab < 16; ++slab) {
      const int kw0 = kwc * 2048 + slab * 128;
      for (int e = t; e < 2048; e += TPB) {
        int bb = e >> 7, j = e & 127;
        sm.x.ysr[e] = y_re[bb * NVIS_ + kw0 + j];
        sm.x.ysi[e] = y_im[bb * NVIS_ + kw0 + j];
      }
      __syncthreads();
      for (int j = 0; j < 128; ++j) {
        const size_t off2 = (size_t)(kw0 + j) * NPX + ps * 128 + p4;
        float4 h4r = *(const float4*)(H_re + off2);
        float4 h4i = *(const float4*)(H_im + off2);
#pragma unroll
        for (int h = 0; h < 2; ++h) {
          int bb = wsub + 8 * h;
          float yr = sm.x.ysr[bb * 128 + j], yi = sm.x.ysi[bb * 128 + j];
          ar[h][0] += yr*h4r.x - yi*h4i.x; ai[h][0] += yr*h4i.x + yi*h4r.x;
          ar[h][1] += yr*h4r.y - yi*h4i.y; ai[h][1] += yr*h4i.y + yi*h4r.y;
          ar[h][2] += yr*h4r.z - yi*h4i.z; ai[h][2] += yr*h4i.z + yi*h4r.z;
          ar[h][3] += yr*h4r.w - yi*h4i.w; ai[h][3] += yr*h4i.w + yi*h4r.w;
        }
      }
      __syncthreads();
    }
#pragma unroll
    for (int h = 0; h < 2; ++h) {
      int bb = wsub + 8 * h;
#pragma unroll
      for (int j = 0; j < 4; ++j) {
        float* pp = ws + WS_X0P_W + ((size_t)((kwc * NB + bb) * NPX + ps * 128 + p4 + j)) * 2;
        AG_STF(pp, ar[h][j]); AG_STF(pp + 1, ai[h][j]);
      }
    }
  }
  gbar(wsu + WS_ROOTA, wsu + 32 * (1 + (bid & 7)), 32, 8u);

  // ================================== SEQUENCER ==================================
  if (bid >= NB * NMEM) {
    const int b = bid - NB * NMEM;
    SeqSM* Q = &sm.q;
    for (int i = t; i < NW * NW; i += TPB) {
      int r = i >> 6, c = i & 63;
      Q->wE[r*65+c] = Ew[i]; Q->wU[r*65+c] = Uw[i]; Q->wM[r*65+c] = Mw[i];
    }
    if (t < NW) { Q->bE[t] = Eb[t]; Q->bU[t] = Ub[t]; Q->bM[t] = Mb[t]; }
    __syncthreads();
    if (niter <= 0) return;

    const int wv = t >> 6, lane = t & 63;
    float ypr = 0.f, ypi = 0.f, tpr = 0.f;
    uint4 su[NMEM];
    uint4 gA[16], gB[16];
#pragma unroll
    for (int q2 = 0; q2 < 16; ++q2) { gA[q2] = make_uint4(0,0,0,0); gB[q2] = make_uint4(0,0,0,0); }
#pragma unroll
    for (int m2 = 0; m2 < NMEM; ++m2) su[m2] = make_uint4(0,0,0,0);

    if (wv == 0) {
      ypr = y_re[b * NVIS_ + lane];
      ypi = y_im[b * NVIS_ + lane];
      // issue s-snapshot for L=0
#pragma unroll
      for (int m2 = 0; m2 < NMEM; ++m2) {
        const uint4* p = (const uint4*)(wsu + WS_SRING_W +
            ((size_t)((b * 8 + 0) * NMEM + m2) * 64 + lane) * 4);
        asm volatile("global_load_dwordx4 %0, %1, off sc0 sc1" : "=v"(su[m2]) : "v"(p));
      }
    }

    const long NTOT = (long)niter * NK;
    for (long L = 0; L < NTOT; ++L) {
      const int k = (int)(L & (NK - 1));
      const int it2 = (int)(L >> 10);
      float zr = 0.f, zi = 0.f;
      // ---------------- phase 1 ----------------
      if (wv == 0) {
        const unsigned want = (unsigned)L + 1u;
        const int slot8 = (int)(L & 7);
        bool first = true;
        for (;;) {
          if (!first) {
#pragma unroll
            for (int m2 = 0; m2 < NMEM; ++m2) {
              const uint4* p = (const uint4*)(wsu + WS_SRING_W +
                  ((size_t)((b * 8 + slot8) * NMEM + m2) * 64 + lane) * 4);
              asm volatile("global_load_dwordx4 %0, %1, off sc0 sc1" : "=v"(su[m2]) : "v"(p));
            }
          }
          asm volatile("s_waitcnt vmcnt(0)" ::: "memory");
          __builtin_amdgcn_sched_barrier(0);
          bool ok = true; float ar = 0.f, ai = 0.f;
#pragma unroll
          for (int m2 = 0; m2 < NMEM; ++m2) {
            ok = ok && (su[m2].z == want);
            ar += __uint_as_float(su[m2].x); ai += __uint_as_float(su[m2].y);
          }
          if (__all((int)ok)) { zr = ar; zi = ai; break; }
          first = false;
          __builtin_amdgcn_s_sleep(1);
        }
      } else if (wv == 1) {           // corrections d=1,2
        float ar = 0.f, ai = 0.f;
        if (k >= 1) {
          const float* rl = Q->rloc[(int)((L - 1) & 3)];
#pragma unroll
          for (int q2 = 0; q2 < 16; ++q2) {
            uint4 u = gA[q2];
            GMAC(u.x, 4*q2+0, rl) GMAC(u.y, 4*q2+1, rl) GMAC(u.z, 4*q2+2, rl) GMAC(u.w, 4*q2+3, rl)
          }
        }
        if (k >= 2) {
          const float* rl = Q->rloc[(int)((L - 2) & 3)];
#pragma unroll
          for (int q2 = 0; q2 < 16; ++q2) {
            uint4 u = gB[q2];
            GMAC(u.x, 4*q2+0, rl) GMAC(u.y, 4*q2+1, rl) GMAC(u.z, 4*q2+2, rl) GMAC(u.w, 4*q2+3, rl)
          }
        }
        Q->ztA[2*lane] = ar * (1.f / NW); Q->ztA[2*lane+1] = ai * (1.f / NW);
      } else if (wv == 2) {           // corrections d=3,4
        float ar = 0.f, ai = 0.f;
        if (k >= 3) {
          const float* rl = Q->rloc[(int)((L - 3) & 3)];
#pragma unroll
          for (int q2 = 0; q2 < 16; ++q2) {
            uint4 u = gA[q2];
            GMAC(u.x, 4*q2+0, rl) GMAC(u.y, 4*q2+1, rl) GMAC(u.z, 4*q2+2, rl) GMAC(u.w, 4*q2+3, rl)
          }
        }
        if (k >= 4) {
          const float* rl = Q->rloc[(int)((L - 4) & 3)];
#pragma unroll
          for (int q2 = 0; q2 < 16; ++q2) {
            uint4 u = gB[q2];
            GMAC(u.x, 4*q2+0, rl) GMAC(u.y, 4*q2+1, rl) GMAC(u.z, 4*q2+2, rl) GMAC(u.w, 4*q2+3, rl)
          }
        }
        Q->ztB[2*lane] = ar * (1.f / NW); Q->ztB[2*lane+1] = ai * (1.f / NW);
      } else {                        // wave3: post r_{L-1}
        if (L >= 1) {
          const unsigned Lr = (unsigned)(L - 1);
          union { float2 f2; unsigned long long u; } cv;
          cv.f2 = make_float2(Q->rpost[2*lane], Q->rpost[2*lane+1]);
          unsigned woff = WS_RRING_W + (((b * 8 + (int)(Lr & 7u)) * 64 + lane)) * 4;
          AG_ST64((unsigned long long*)(wsu + woff), cv.u);
          asm volatile("s_waitcnt vmcnt(0)" ::: "memory");
          AG_STU(wsu + woff + 2, Lr + 1u);
        }
      }
      BARL();
      // ---------------- phase 2 ----------------
      if (wv == 0) {
        float z_r = zr + Q->ztA[2*t] + Q->ztB[2*t];
        float z_i = zi + Q->ztA[2*t+1] + Q->ztB[2*t+1];
        float dr = ypr - z_r, di = ypi - z_i;
        Q->r2s[t] = dr*dr + di*di;
        Q->tpl[t] = (it2 == 0) ? 0.f : tpr;
        asm volatile("s_waitcnt lgkmcnt(0)" ::: "memory");
        float e = Q->bE[t];
#pragma unroll 16
        for (int j2 = 0; j2 < 64; ++j2) e += Q->wE[t*65+j2] * Q->r2s[j2];
        Q->hts[t] = 1.f / (1.f + __expf(-e));
        asm volatile("s_waitcnt lgkmcnt(0)" ::: "memory");
        float a = Q->bU[t] + Q->bM[t];
#pragma unroll 16
        for (int j2 = 0; j2 < 64; ++j2)
          a += Q->wU[t*65+j2] * Q->hts[j2] + Q->wM[t*65+j2] * Q->tpl[j2];
        float wn = fmaxf(a, 0.f);
        tau[((size_t)b * NK + k) * NW + t] = wn;
        float rr = ypr - z_r * wn, ri = ypi - z_i * wn;
        Q->rloc[(int)(L & 3)][2*t] = rr; Q->rloc[(int)(L & 3)][2*t+1] = ri;
        Q->rpost[2*t] = rr; Q->rpost[2*t+1] = ri;
        if (L + 1 < NTOT) {
          const int k2 = (int)((L + 1) & (NK - 1));
          ypr = y_re[b * NVIS_ + k2 * NW + t];
          ypi = y_im[b * NVIS_ + k2 * NW + t];
          tpr = tau[((size_t)b * NK + k2) * NW + t];
          const int slotn = (int)((L + 1) & 7);
#pragma unroll
          for (int m2 = 0; m2 < NMEM; ++m2) {
            const uint4* p = (const uint4*)(wsu + WS_SRING_W +
                ((size_t)((b * 8 + slotn) * NMEM + m2) * 64 + lane) * 4);
            asm volatile("global_load_dwordx4 %0, %1, off sc0 sc1" : "=v"(su[m2]) : "v"(p));
          }
        }
      } else if (wv == 1) {           // prefetch G for target k+1: d=1 (j'=k), d=2 (j'=k-1)
        const int kn = (int)((L + 1) & (NK - 1));
        if (L + 1 < NTOT && kn >= 1) {
          const uint4* gp = (const uint4*)(Gu + ((size_t)((kn - 1) * NDC + 0) * 64 + lane) * 64);
#pragma unroll
          for (int q2 = 0; q2 < 16; ++q2) gA[q2] = gp[q2];
        }
        if (L + 1 < NTOT && kn >= 2) {
          const uint4* gp = (const uint4*)(Gu + ((size_t)((kn - 2) * NDC + 1) * 64 + lane) * 64);
#pragma unroll
          for (int q2 = 0; q2 < 16; ++q2) gB[q2] = gp[q2];
        }
      } else if (wv == 2) {           // d=3 (j'=k-2), d=4 (j'=k-3)
        const int kn = (int)((L + 1) & (NK - 1));
        if (L + 1 < NTOT && kn >= 3) {
          const uint4* gp = (const uint4*)(Gu + ((size_t)((kn - 3) * NDC + 2) * 64 + lane) * 64);
#pragma unroll
          for (int q2 = 0; q2 < 16; ++q2) gA[q2] = gp[q2];
        }
        if (L + 1 < NTOT && kn >= 4) {
          const uint4* gp = (const uint4*)(Gu + ((size_t)((kn - 4) * NDC + 3) * 64 + lane) * 64);
#pragma unroll
          for (int q2 = 0; q2 < 16; ++q2) gB[q2] = gp[q2];
        }
      }
      BARL();
      // sweep boundary: post r_{NK-1} immediately (members need it for C(NK-1))
      if (k == NK - 1 && wv == 3) {
        union { float2 f2; unsigned long long u; } cv;
        cv.f2 = make_float2(Q->rpost[2*lane], Q->rpost[2*lane+1]);
        unsigned woff = WS_RRING_W + (((b * 8 + (int)(L & 7u)) * 64 + lane)) * 4;
        AG_ST64((unsigned long long*)(wsu + woff), cv.u);
        asm volatile("s_waitcnt vmcnt(0)" ::: "memory");
        AG_STU(wsu + woff + 2, (unsigned)L + 1u);
      }
    }
    return;
  }

  // ================================== MEMBER ==================================
  const int b = bid / NMEM;
  const int m = bid % NMEM;
  const int off = m * 68;
  const int cnt = (m == NMEM - 1) ? 72 : 68;
  const int nq = cnt >> 2;
  MemSM* M = &sm.m;

  // x0 stage 2
  if (t < cnt * 2) {
    int p = t >> 1, c = t & 1;
    float s = 0.f;
    for (int kwc = 0; kwc < 32; ++kwc)
      s += AG_LDF(ws + WS_X0P_W + ((size_t)((kwc * NB + b) * NPX + off + p)) * 2 + c);
    M->xs[2 * p + c] = s;
  }
  __syncthreads();

  if (niter <= 0) {
    if (t < cnt) {
      float xr = M->xs[2*t], xi = M->xs[2*t+1];
      out[b * NPX + off + t] = sqrtf(xr*xr + xi*xi);
    }
    return;
  }

  float4 cr[8], ci[8];      // C tile (step j)
  float4 ar8[8], ai8[8];    // A tile (step j+WWIN)

  auto load_C = [&](int k) {
    if (g5 < nq) {
      const size_t rb = ((size_t)k * NW + wsub) * NPX + off + p4;
#pragma unroll
      for (int i = 0; i < 8; ++i) {
        cr[i] = *(const float4*)(H_re + rb + (size_t)i * 8 * NPX);
        ci[i] = *(const float4*)(H_im + rb + (size_t)i * 8 * NPX);
      }
    }
  };
  auto load_A = [&](int k) {
    if (g5 < nq) {
      const size_t rb = ((size_t)k * NW + wsub) * NPX + off + p4;
#pragma unroll
      for (int i = 0; i < 8; ++i) {
        ar8[i] = *(const float4*)(H_re + rb + (size_t)i * 8 * NPX);
        ai8[i] = *(const float4*)(H_im + rb + (size_t)i * 8 * NPX);
      }
    }
  };
  auto compute_A = [&]() {          // s = x . conj(H) using ar8/ai8; writes partl
    float zpr[8], zpi[8];
    float4 xq0 = make_float4(0,0,0,0), xq1 = make_float4(0,0,0,0);
    if (g5 < nq) { xq0 = *(const float4*)&M->xs[p4*2]; xq1 = *(const float4*)&M->xs[p4*2+4]; }
#pragma unroll
    for (int i = 0; i < 8; ++i) {
      float zr = 0.f, zi = 0.f;
      if (g5 < nq) {
        zr = xq0.x*ar8[i].x + xq0.y*ai8[i].x + xq0.z*ar8[i].y + xq0.w*ai8[i].y
           + xq1.x*ar8[i].z + xq1.y*ai8[i].z + xq1.z*ar8[i].w + xq1.w*ai8[i].w;
        zi = xq0.y*ar8[i].x - xq0.x*ai8[i].x + xq0.w*ar8[i].y - xq0.z*ai8[i].y
           + xq1.y*ar8[i].z - xq1.x*ai8[i].z + xq1.w*ar8[i].w - xq1.z*ai8[i].w;
      }
#pragma unroll
      for (int msk = 16; msk >= 1; msk >>= 1) {
        zr += __shfl_xor(zr, msk); zi += __shfl_xor(zi, msk);
      }
      zpr[i] = zr; zpi[i] = zi;
    }
    if (g5 == 0) {
#pragma unroll
      for (int i = 0; i < 8; ++i) {
        M->partl[(8*i + wsub)*2]     = zpr[i];
        M->partl[(8*i + wsub)*2 + 1] = zpi[i];
      }
    }
  };
  auto post_s = [&](unsigned Ls) {  // wave0 (t<64)
    const int slot8 = (int)(Ls & 7u);
    union { float2 f2; unsigned long long u; } cv;
    cv.f2 = make_float2(M->partl[2*t], M->partl[2*t+1]);
    unsigned woff = WS_SRING_W + ((size_t)((b * 8 + slot8) * NMEM + m) * 64 + t) * 4;
    AG_ST64((unsigned long long*)(wsu + woff), cv.u);
    asm volatile("s_waitcnt vmcnt(0)" ::: "memory");
    AG_STU(wsu + woff + 2, Ls + 1u);
  };
  auto poll_r = [&](unsigned Lr, int buf) {  // wave1 (t in [64,128)); lane l
    const int l = t - 64;
    const unsigned want = Lr + 1u;
    const uint4* p = (const uint4*)(wsu + WS_RRING_W +
        ((size_t)((b * 8 + (int)(Lr & 7u)) * 64 + l)) * 4);
    uint4 u;
    for (;;) {
      asm volatile("global_load_dwordx4 %0, %1, off sc0 sc1\n\ts_waitcnt vmcnt(0)"
                   : "=v"(u) : "v"(p) : "memory");
      if (__all((int)(u.z == want))) break;
      __builtin_amdgcn_s_sleep(1);
    }
    M->rsbuf[buf][2*l]   = __uint_as_float(u.x);
    M->rsbuf[buf][2*l+1] = __uint_as_float(u.y);
  };

  for (int iter = 0; iter < niter; ++iter) {
    const unsigned L0 = (unsigned)(iter * NK);
    // ---- prologue: post s_0..s_{W-1} from x_start ----
    for (int kk = 0; kk < WWIN; ++kk) {
      load_A(kk);
      compute_A();
      BARL();
      if (t < 64) post_s(L0 + (unsigned)kk);
      BARL();
    }
    load_C(0);
    load_A(WWIN);
    if (t >= 64 && t < 128) poll_r(L0, 0);
    BARL();

    for (int j = 0; j < NK; ++j) {
      const int cur = j & 1;
      // ---- phase 1: C(j) from regs x rsbuf[cur] -> redc ----
      if (g5 < nq) {
        const float* rsb = M->rsbuf[cur];
        float dre[4] = {0,0,0,0}, dim[4] = {0,0,0,0};
#pragma unroll
        for (int i = 0; i < 8; ++i) {
          int w = 8*i + wsub;
          float rr = rsb[2*w], ri = rsb[2*w+1];
          dre[0] += rr*cr[i].x - ri*ci[i].x; dim[0] += rr*ci[i].x + ri*cr[i].x;
          dre[1] += rr*cr[i].y - ri*ci[i].y; dim[1] += rr*ci[i].y + ri*cr[i].y;
          dre[2] += rr*cr[i].z - ri*ci[i].z; dim[2] += rr*ci[i].z + ri*cr[i].z;
          dre[3] += rr*cr[i].w - ri*ci[i].w; dim[3] += rr*ci[i].w + ri*cr[i].w;
        }
#pragma unroll
        for (int q = 0; q < 4; ++q) {
          M->redc[(2*q)   * ESTR + wsub*20 + g5] = dre[q];
          M->redc[(2*q+1) * ESTR + wsub*20 + g5] = dim[q];
        }
      }
      BARL();
      // ---- phase 2: xs update ----
      if (t < cnt * 2) {
        int p = t >> 1, c = t & 1;
        float s = 0.f;
#pragma unroll
        for (int u2 = 0; u2 < 8; ++u2)
          s += M->redc[((p & 3)*2 + c) * ESTR + u2*20 + (p >> 2)];
        M->xs[2*p + c] += s * (1.f / NW);
      }
      BARL();
      // ---- phase 3: A(j+W) ----
      const int ka = j + WWIN;
      if (ka < NK) compute_A();
      BARL();
      // ---- phase 4: post/poll + issue next tiles ----
      if (ka < NK && t < 64) post_s(L0 + (unsigned)ka);
      if (j + 1 < NK && t >= 64 && t < 128) poll_r(L0 + (unsigned)(j + 1), (j + 1) & 1);
      if (j + 1 < NK) load_C(j + 1);
      if (ka + 1 < NK) load_A(ka + 1);
      BARL();
    }

    // ---- global soft-threshold (members only) ----
    {
      float ax = 0.f;
      if (t < cnt) {
        float xr = M->xs[2*t], xi = M->xs[2*t+1];
        ax = sqrtf(xr*xr + xi*xi);
        M->axs[t] = ax;
      } else if (t < 128) M->axs[t] = 0.f;
      __syncthreads();
      for (int o = 64; o > 0; o >>= 1) {
        if (t < o) M->axs[t] = fmaxf(M->axs[t], M->axs[t + o]);
        __syncthreads();
      }
      if (t == 0)
        __hip_atomic_fetch_max(wsu + WS_GMAX + (iter & 63), __float_as_uint(M->axs[0]),
                               __ATOMIC_RELAXED, __HIP_MEMORY_SCOPE_AGENT);
      gbar(wsu + WS_ROOTB, wsu + WS_LEAFB + 32 * (bid & 7), 30, 8u * (unsigned)(iter + 1));
      float gm = __uint_as_float(__hip_atomic_load(wsu + WS_GMAX + (iter & 63),
                                 __ATOMIC_RELAXED, __HIP_MEMORY_SCOPE_AGENT));
      if (t < cnt) {
        float mag = fmaxf(ax - thr * gm, 0.f);
        float sc = (ax > 0.f) ? (mag / ax) : 0.f;
        M->xs[2*t] *= sc; M->xs[2*t+1] *= sc;
        if (iter == niter - 1) out[b * NPX + off + t] = mag;
      }
      __syncthreads();
    }
  }
}

extern "C" void kernel_launch(void* const* d_in, const int* in_sizes, int n_in,
                              void* d_out, int out_size, void* d_ws, size_t ws_size,
                              hipStream_t stream) {
  const float* y_re = (const float*)d_in[0];
  const float* y_im = (const float*)d_in[1];
  const float* H_re = (const float*)d_in[2];
  const float* H_im = (const float*)d_in[3];
  const float* Ew   = (const float*)d_in[4];
  const float* Eb   = (const float*)d_in[5];
  const float* Uw   = (const float*)d_in[6];
  const float* Ub   = (const float*)d_in[7];
  const float* Mw   = (const float*)d_in[8];
  const float* Mb   = (const float*)d_in[9];
  const float* thr  = (const float*)d_in[10];
  const int*  niter = (const int*)d_in[11];
  (void)in_sizes; (void)n_in; (void)out_size; (void)ws_size;

  robbi_init<<<512, 256, 0, stream>>>((unsigned*)d_ws);
  robbi_gram<<<NK * 2, 256, 0, stream>>>(H_re, H_im, (float*)d_ws);
  robbi_pipe<<<NWG, TPB, 0, stream>>>(
      y_re, y_im, H_re, H_im, Ew, Eb, Uw, Ub, Mw, Mb, thr, niter,
      (float*)d_out, (float*)d_ws);
}